// Round 15
// baseline (596.139 us; speedup 1.0000x reference)
//
#include <hip/hip_runtime.h>
#include <hip/hip_fp16.h>

#define NGRAPH 100000
#define NEDGE  1600000
#define HID    128
#define SCAN_B 512
#define NBLK   ((NGRAPH + SCAN_B - 1) / SCAN_B)   // 196
#define TILE   64                                  // nodes per k_mlp block
#define LPAD   (HID + 2)                           // LDS row stride: 49.9KB total

__device__ __forceinline__ int e_src(const int* ei, int is64, int e) {
    return is64 ? ei[2 * e] : ei[e];
}
__device__ __forceinline__ int e_dst(const int* ei, int is64, int e) {
    return is64 ? ei[2 * NEDGE + 2 * e] : ei[NEDGE + e];
}

// ---------- combined features + deg/fill init + int64-detect (block 0, wave 0) ----------
__global__ void k_prep(const float* __restrict__ obs, const int* __restrict__ ei,
                       float* __restrict__ comb, int* __restrict__ deg,
                       int* __restrict__ fill, int* __restrict__ flag) {
    if (blockIdx.x == 0 && threadIdx.x < 64) {
        int v = ei[2 * threadIdx.x + 1];           // odd words of src region
        unsigned long long b = __ballot(v != 0);
        if (threadIdx.x == 0) flag[0] = (b == 0ull) ? 1 : 0;  // 1 => int64
    }
    int i = blockIdx.x * blockDim.x + threadIdx.x;
    if (i >= NGRAPH) return;
    int n = i / 20, c = i % 20;
    const float* nf = obs + 3 + n * 4;
    const float* cf = obs + 3 + 20000 + c * 3;
    float* o = comb + i * 7;
    o[0] = nf[0]; o[1] = nf[1]; o[2] = nf[2]; o[3] = nf[3];
    o[4] = cf[0]; o[5] = cf[1]; o[6] = cf[2];
    deg[i] = 0;
    fill[i] = 0;
}

__global__ void k_deg(const int* __restrict__ ei, const int* __restrict__ flag,
                      int* __restrict__ deg) {
    int e = blockIdx.x * blockDim.x + threadIdx.x;
    if (e >= NEDGE) return;
    atomicAdd(&deg[e_dst(ei, flag[0], e)], 1);
}

// ---------- exclusive scan of deg -> rowptr (3-kernel hierarchical); also dinv ----------
__global__ void __launch_bounds__(SCAN_B) k_scan1(const int* __restrict__ deg,
                                                  int* __restrict__ rowptr,
                                                  int* __restrict__ sums,
                                                  float* __restrict__ dinv) {
    __shared__ int sh[SCAN_B];
    int t = threadIdx.x;
    int i = blockIdx.x * SCAN_B + t;
    int val = (i < NGRAPH) ? deg[i] : 0;
    if (i < NGRAPH) dinv[i] = rsqrtf((float)(val + 1));   // +1: self loop
    sh[t] = val;
    __syncthreads();
    for (int o = 1; o < SCAN_B; o <<= 1) {
        int x = (t >= o) ? sh[t - o] : 0;
        __syncthreads();
        sh[t] += x;
        __syncthreads();
    }
    if (i < NGRAPH) rowptr[i] = sh[t] - val;          // exclusive within block
    if (t == SCAN_B - 1) sums[blockIdx.x] = sh[t];    // block total
}

__global__ void __launch_bounds__(256) k_scan2(int* __restrict__ sums) {
    __shared__ int sh[256];
    int t = threadIdx.x;
    int val = (t < NBLK) ? sums[t] : 0;
    sh[t] = val;
    __syncthreads();
    for (int o = 1; o < 256; o <<= 1) {
        int x = (t >= o) ? sh[t - o] : 0;
        __syncthreads();
        sh[t] += x;
        __syncthreads();
    }
    if (t < NBLK) sums[t] = sh[t] - val;              // exclusive block offsets
}

__global__ void __launch_bounds__(SCAN_B) k_scan3(int* __restrict__ rowptr,
                                                  const int* __restrict__ sums) {
    int i = blockIdx.x * SCAN_B + threadIdx.x;
    if (i < NGRAPH) rowptr[i] += sums[blockIdx.x];
}

// ---------- scatter edges into packed CSR slots: int2{src, w-bits} ----------
__global__ void k_fill(const int* __restrict__ ei, const int* __restrict__ flag,
                       const float* __restrict__ dinv,
                       const int* __restrict__ rowptr, int* __restrict__ fill,
                       int2* __restrict__ csr) {
    int e = blockIdx.x * blockDim.x + threadIdx.x;
    if (e >= NEDGE) return;
    int is64 = flag[0];
    int s = e_src(ei, is64, e);
    int d = e_dst(ei, is64, e);
    int pos = rowptr[d] + atomicAdd(&fill[d], 1);
    csr[pos] = make_int2(s, __float_as_int(dinv[s] * dinv[d]));
}

// ---------- fused GCN layer 1: CSR agg (7-dim) + [7->128] matmul + ReLU -> fp16 x1 ----
__global__ void __launch_bounds__(256) k_gcn1(const int* __restrict__ rowptr,
                                              const int* __restrict__ deg,
                                              const int2* __restrict__ csr,
                                              const float* __restrict__ dinv,
                                              const float* __restrict__ comb,
                                              const float* __restrict__ W1,
                                              const float* __restrict__ b1,
                                              __half* __restrict__ x1) {
    __shared__ float agg_s[32][8];
    int g = threadIdx.x >> 3;                  // node within block
    int f = threadIdx.x & 7;
    int d = blockIdx.x * 32 + g;
    if (f < 7) {
        int start = rowptr[d], n = deg[d];
        float acc = 0.0f;
        for (int j = 0; j < n; ++j) {
            int2 ed = csr[start + j];
            acc += __int_as_float(ed.y) * comb[ed.x * 7 + f];
        }
        float dv = dinv[d];
        acc += dv * dv * comb[d * 7 + f];      // self loop
        agg_s[g][f] = acc;
    }
    __syncthreads();
    float a[7];
    #pragma unroll
    for (int q = 0; q < 7; ++q) a[q] = agg_s[g][q];   // LDS broadcast per node
    int h0 = f * 16;
    #pragma unroll
    for (int j = 0; j < 4; ++j) {
        int h = h0 + j * 4;
        float4 acc4 = *reinterpret_cast<const float4*>(b1 + h);
        #pragma unroll
        for (int q = 0; q < 7; ++q) {
            float4 w = *reinterpret_cast<const float4*>(W1 + q * HID + h);
            acc4.x = fmaf(a[q], w.x, acc4.x);
            acc4.y = fmaf(a[q], w.y, acc4.y);
            acc4.z = fmaf(a[q], w.z, acc4.z);
            acc4.w = fmaf(a[q], w.w, acc4.w);
        }
        __half2 h01 = __floats2half2_rn(fmaxf(acc4.x, 0.0f), fmaxf(acc4.y, 0.0f));
        __half2 h23 = __floats2half2_rn(fmaxf(acc4.z, 0.0f), fmaxf(acc4.w, 0.0f));
        uint2 pk;
        pk.x = *reinterpret_cast<unsigned int*>(&h01);
        pk.y = *reinterpret_cast<unsigned int*>(&h23);
        *reinterpret_cast<uint2*>(x1 + (size_t)d * HID + h) = pk;   // 8B aligned
    }
}

// ---------- fused dense tail + layer-2 aggregation ----------
// Phase 0 (fused k_agg2): each wave gathers 16 nodes' agg2 rows (CSR over fp16 x1,
// lane = half2 col) straight into as_ -- no global agg2 round-trip (saves 102MB),
// and gather (HBM-bound) overlaps other blocks' MAC phases (LDS/VALU-bound, m114).
// Phases A/B/C: r13 structure unchanged (conflict-free, LDS-throughput-bound 101us).
// LPAD=130: 49.9KB total LDS, aiming 3 blocks/CU (r13 measured 2 at 50.7KB).
__device__ __forceinline__ void fmad(float4& acc, float s, const float4 w) {
    acc.x = fmaf(s, w.x, acc.x);
    acc.y = fmaf(s, w.y, acc.y);
    acc.z = fmaf(s, w.z, acc.z);
    acc.w = fmaf(s, w.w, acc.w);
}
__device__ __forceinline__ float4 relu4(float4 v) {
    float4 r;
    r.x = fmaxf(v.x, 0.0f); r.y = fmaxf(v.y, 0.0f);
    r.z = fmaxf(v.z, 0.0f); r.w = fmaxf(v.w, 0.0f);
    return r;
}

__global__ void __launch_bounds__(256, 3) k_mlp(const int* __restrict__ rowptr,
                                                const int* __restrict__ deg,
                                                const int2* __restrict__ csr,
                                                const float* __restrict__ dinv,
                                                const __half2* __restrict__ x1,
                                                const float* __restrict__ W2,
                                                const float* __restrict__ b2,
                                                const float* __restrict__ fc1w,
                                                const float* __restrict__ fc1b,
                                                const float* __restrict__ fc2w,
                                                const float* __restrict__ fc2b,
                                                float* __restrict__ out) {
    __shared__ float as_[TILE][LPAD];      // agg2 tile, then x2 tile (33.3KB)
    __shared__ float ws[32][LPAD];         // 32 staged weight rows (16.6KB)
    const int tid = threadIdx.x;
    const int tx = tid & 15;               // two output cols: hA=tx*4, hB=64+tx*4
    const int ty = tid >> 4;               // nodes ty*4 .. ty*4+3
    const int n0 = blockIdx.x * TILE;      // tail block: 32 valid nodes, guarded
    const int hA = tx * 4;
    const int hB = 64 + tx * 4;

    // ---- phase 0: gather agg2 tile into as_ (1 wave per 16 nodes, lane=half2 col) ----
    {
        int wave = tid >> 6;               // 0..3
        int lane = tid & 63;
        for (int q = 0; q < 16; ++q) {
            int row = wave * 16 + q;
            int nd = n0 + row;
            if (nd >= NGRAPH) nd = NGRAPH - 1;   // duplicate gather; out writes guarded
            int start = rowptr[nd], n = deg[nd];
            float2 acc = {0.0f, 0.0f};
            int j = 0;
            for (; j + 2 <= n; j += 2) {
                int2 e0 = csr[start + j];
                int2 e1 = csr[start + j + 1];
                float w0 = __int_as_float(e0.y);
                float w1 = __int_as_float(e1.y);
                float2 v0 = __half22float2(x1[(size_t)e0.x * 64 + lane]);
                float2 v1 = __half22float2(x1[(size_t)e1.x * 64 + lane]);
                acc.x = fmaf(w0, v0.x, acc.x);
                acc.y = fmaf(w0, v0.y, acc.y);
                acc.x = fmaf(w1, v1.x, acc.x);
                acc.y = fmaf(w1, v1.y, acc.y);
            }
            if (j < n) {
                int2 e0 = csr[start + j];
                float w0 = __int_as_float(e0.y);
                float2 v0 = __half22float2(x1[(size_t)e0.x * 64 + lane]);
                acc.x = fmaf(w0, v0.x, acc.x);
                acc.y = fmaf(w0, v0.y, acc.y);
            }
            float dv = dinv[nd];
            float wsl = dv * dv;
            float2 v = __half22float2(x1[(size_t)nd * 64 + lane]);
            acc.x = fmaf(wsl, v.x, acc.x);
            acc.y = fmaf(wsl, v.y, acc.y);
            *reinterpret_cast<float2*>(&as_[row][lane * 2]) = acc;
        }
    }
    // as_ writes are covered by the first ws-stage __syncthreads below.

    // ---- phase A: x2 = relu(agg2 @ W2 + b2) ----
    float4 cA[4], cB[4];
    {
        float4 bA = *reinterpret_cast<const float4*>(b2 + hA);
        float4 bB = *reinterpret_cast<const float4*>(b2 + hB);
        #pragma unroll
        for (int r = 0; r < 4; ++r) { cA[r] = bA; cB[r] = bB; }
    }
    for (int ks = 0; ks < HID; ks += 32) {
        #pragma unroll
        for (int q = 0; q < 4; ++q) {
            int idx = (q * 256 + tid) * 4;
            int row = idx >> 7, col = idx & 127;
            *reinterpret_cast<float4*>(&ws[row][col]) =
                *reinterpret_cast<const float4*>(W2 + (size_t)(ks + row) * HID + col);
        }
        __syncthreads();                    // covers phase-0 as_ writes on ks==0
        #pragma unroll
        for (int k = 0; k < 32; k += 4) {
            float4 wA0 = *reinterpret_cast<const float4*>(&ws[k + 0][hA]);
            float4 wB0 = *reinterpret_cast<const float4*>(&ws[k + 0][hB]);
            float4 wA1 = *reinterpret_cast<const float4*>(&ws[k + 1][hA]);
            float4 wB1 = *reinterpret_cast<const float4*>(&ws[k + 1][hB]);
            float4 wA2 = *reinterpret_cast<const float4*>(&ws[k + 2][hA]);
            float4 wB2 = *reinterpret_cast<const float4*>(&ws[k + 2][hB]);
            float4 wA3 = *reinterpret_cast<const float4*>(&ws[k + 3][hA]);
            float4 wB3 = *reinterpret_cast<const float4*>(&ws[k + 3][hB]);
            #pragma unroll
            for (int r = 0; r < 4; ++r) {
                float4 a = *reinterpret_cast<const float4*>(&as_[ty * 4 + r][ks + k]);
                fmad(cA[r], a.x, wA0); fmad(cB[r], a.x, wB0);
                fmad(cA[r], a.y, wA1); fmad(cB[r], a.y, wB1);
                fmad(cA[r], a.z, wA2); fmad(cB[r], a.z, wB2);
                fmad(cA[r], a.w, wA3); fmad(cB[r], a.w, wB3);
            }
        }
        __syncthreads();                    // protect ws for next stage
    }
    // write x2 into as_ (all phase-A reads completed at the trailing sync)
    #pragma unroll
    for (int r = 0; r < 4; ++r) {
        *reinterpret_cast<float4*>(&as_[ty * 4 + r][hA]) = relu4(cA[r]);
        *reinterpret_cast<float4*>(&as_[ty * 4 + r][hB]) = relu4(cB[r]);
    }

    // ---- phase B: x3 = relu(x2 @ fc1w + fc1b) ----
    float4 dA[4], dB[4];
    {
        float4 bA = *reinterpret_cast<const float4*>(fc1b + hA);
        float4 bB = *reinterpret_cast<const float4*>(fc1b + hB);
        #pragma unroll
        for (int r = 0; r < 4; ++r) { dA[r] = bA; dB[r] = bB; }
    }
    for (int ks = 0; ks < HID; ks += 32) {
        #pragma unroll
        for (int q = 0; q < 4; ++q) {
            int idx = (q * 256 + tid) * 4;
            int row = idx >> 7, col = idx & 127;
            *reinterpret_cast<float4*>(&ws[row][col]) =
                *reinterpret_cast<const float4*>(fc1w + (size_t)(ks + row) * HID + col);
        }
        __syncthreads();                    // also makes x2 writes visible (ks==0)
        #pragma unroll
        for (int k = 0; k < 32; k += 4) {
            float4 wA0 = *reinterpret_cast<const float4*>(&ws[k + 0][hA]);
            float4 wB0 = *reinterpret_cast<const float4*>(&ws[k + 0][hB]);
            float4 wA1 = *reinterpret_cast<const float4*>(&ws[k + 1][hA]);
            float4 wB1 = *reinterpret_cast<const float4*>(&ws[k + 1][hB]);
            float4 wA2 = *reinterpret_cast<const float4*>(&ws[k + 2][hA]);
            float4 wB2 = *reinterpret_cast<const float4*>(&ws[k + 2][hB]);
            float4 wA3 = *reinterpret_cast<const float4*>(&ws[k + 3][hA]);
            float4 wB3 = *reinterpret_cast<const float4*>(&ws[k + 3][hB]);
            #pragma unroll
            for (int r = 0; r < 4; ++r) {
                float4 a = *reinterpret_cast<const float4*>(&as_[ty * 4 + r][ks + k]);
                fmad(dA[r], a.x, wA0); fmad(dB[r], a.x, wB0);
                fmad(dA[r], a.y, wA1); fmad(dB[r], a.y, wB1);
                fmad(dA[r], a.z, wA2); fmad(dB[r], a.z, wB2);
                fmad(dA[r], a.w, wA3); fmad(dB[r], a.w, wB3);
            }
        }
        __syncthreads();
    }

    // ---- phase C: out = x3 @ fc2w + fc2b (reduce over 16 tx lanes) ----
    float4 wqA = *reinterpret_cast<const float4*>(fc2w + hA);
    float4 wqB = *reinterpret_cast<const float4*>(fc2w + hB);
    float p[4];
    #pragma unroll
    for (int r = 0; r < 4; ++r) {
        float4 rA = relu4(dA[r]);
        float4 rB = relu4(dB[r]);
        p[r] = rA.x * wqA.x + rA.y * wqA.y + rA.z * wqA.z + rA.w * wqA.w
             + rB.x * wqB.x + rB.y * wqB.y + rB.z * wqB.z + rB.w * wqB.w;
    }
    #pragma unroll
    for (int m = 1; m < 16; m <<= 1) {     // xor-mask < 16 stays within the tx group
        #pragma unroll
        for (int r = 0; r < 4; ++r) p[r] += __shfl_xor(p[r], m);
    }
    if (tx == 0) {
        float bq = fc2b[0];
        int nb = n0 + ty * 4;
        #pragma unroll
        for (int r = 0; r < 4; ++r)
            if (nb + r < NGRAPH) out[nb + r] = p[r] + bq;
    }
}

extern "C" void kernel_launch(void* const* d_in, const int* in_sizes, int n_in,
                              void* d_out, int out_size, void* d_ws, size_t ws_size,
                              hipStream_t stream) {
    const float* obs  = (const float*)d_in[0];
    const int*   ei   = (const int*)d_in[1];
    const float* W1   = (const float*)d_in[2];
    const float* b1   = (const float*)d_in[3];
    const float* W2   = (const float*)d_in[4];
    const float* b2   = (const float*)d_in[5];
    const float* fc1w = (const float*)d_in[6];
    const float* fc1b = (const float*)d_in[7];
    const float* fc2w = (const float*)d_in[8];
    const float* fc2b = (const float*)d_in[9];
    float* out = (float*)d_out;

    char* base = (char*)d_ws;
    size_t off = 0;
    auto take = [&](size_t bytes) {
        char* p = base + off;
        off += (bytes + 255) & ~(size_t)255;
        return p;
    };
    int*    deg     = (int*)take((size_t)NGRAPH * 4);
    int*    rowptr  = (int*)take((size_t)NGRAPH * 4);
    int*    fill    = (int*)take((size_t)NGRAPH * 4);
    int*    sums    = (int*)take((size_t)NBLK * 4);
    float*  dinv    = (float*)take((size_t)NGRAPH * 4);
    int2*   csr     = (int2*)take((size_t)NEDGE * 8);
    float*  comb    = (float*)take((size_t)NGRAPH * 7 * 4);
    __half* x1      = (__half*)take((size_t)NGRAPH * HID * 2);
    int*    flag    = (int*)take(256);

    k_prep<<<(NGRAPH + 255) / 256, 256, 0, stream>>>(obs, ei, comb, deg, fill, flag);
    k_deg<<<(NEDGE + 255) / 256, 256, 0, stream>>>(ei, flag, deg);
    k_scan1<<<NBLK, SCAN_B, 0, stream>>>(deg, rowptr, sums, dinv);
    k_scan2<<<1, 256, 0, stream>>>(sums);
    k_scan3<<<NBLK, SCAN_B, 0, stream>>>(rowptr, sums);
    k_fill<<<(NEDGE + 255) / 256, 256, 0, stream>>>(ei, flag, dinv, rowptr, fill, csr);
    k_gcn1<<<NGRAPH / 32, 256, 0, stream>>>(rowptr, deg, csr, dinv,
                                            comb, W1, b1, x1);
    k_mlp<<<(NGRAPH + TILE - 1) / TILE, 256, 0, stream>>>(rowptr, deg, csr, dinv,
                                                          (const __half2*)x1,
                                                          W2, b2, fc1w, fc1b,
                                                          fc2w, fc2b, out);
}

// Round 16
// 450.142 us; speedup vs baseline: 1.3243x; 1.3243x over previous
//
#include <hip/hip_runtime.h>
#include <hip/hip_fp16.h>

#define NGRAPH 100000
#define NEDGE  1600000
#define HID    128
#define SCAN_B 512
#define NBLK   ((NGRAPH + SCAN_B - 1) / SCAN_B)   // 196
#define TILE   64                                  // nodes per k_mlp block
#define LPAD   (HID + 2)                           // LDS row stride

__device__ __forceinline__ int e_src(const int* ei, int is64, int e) {
    return is64 ? ei[2 * e] : ei[e];
}
__device__ __forceinline__ int e_dst(const int* ei, int is64, int e) {
    return is64 ? ei[2 * NEDGE + 2 * e] : ei[NEDGE + e];
}

// ---------- combined features + deg init + int64-detect (block 0, wave 0) ----------
__global__ void k_prep(const float* __restrict__ obs, const int* __restrict__ ei,
                       float* __restrict__ comb, int* __restrict__ deg,
                       int* __restrict__ flag) {
    if (blockIdx.x == 0 && threadIdx.x < 64) {
        int v = ei[2 * threadIdx.x + 1];           // odd words of src region
        unsigned long long b = __ballot(v != 0);
        if (threadIdx.x == 0) flag[0] = (b == 0ull) ? 1 : 0;  // 1 => int64
    }
    int i = blockIdx.x * blockDim.x + threadIdx.x;
    if (i >= NGRAPH) return;
    int n = i / 20, c = i % 20;
    const float* nf = obs + 3 + n * 4;
    const float* cf = obs + 3 + 20000 + c * 3;
    float* o = comb + i * 7;
    o[0] = nf[0]; o[1] = nf[1]; o[2] = nf[2]; o[3] = nf[3];
    o[4] = cf[0]; o[5] = cf[1]; o[6] = cf[2];
    deg[i] = 0;
}

__global__ void k_deg(const int* __restrict__ ei, const int* __restrict__ flag,
                      int* __restrict__ deg) {
    int e = blockIdx.x * blockDim.x + threadIdx.x;
    if (e >= NEDGE) return;
    atomicAdd(&deg[e_dst(ei, flag[0], e)], 1);
}

// ---------- exclusive scan of deg -> rowptr (3-kernel hierarchical); also dinv ----------
__global__ void __launch_bounds__(SCAN_B) k_scan1(const int* __restrict__ deg,
                                                  int* __restrict__ rowptr,
                                                  int* __restrict__ sums,
                                                  float* __restrict__ dinv) {
    __shared__ int sh[SCAN_B];
    int t = threadIdx.x;
    int i = blockIdx.x * SCAN_B + t;
    int val = (i < NGRAPH) ? deg[i] : 0;
    if (i < NGRAPH) dinv[i] = rsqrtf((float)(val + 1));   // +1: self loop
    sh[t] = val;
    __syncthreads();
    for (int o = 1; o < SCAN_B; o <<= 1) {
        int x = (t >= o) ? sh[t - o] : 0;
        __syncthreads();
        sh[t] += x;
        __syncthreads();
    }
    if (i < NGRAPH) rowptr[i] = sh[t] - val;          // exclusive within block
    if (t == SCAN_B - 1) sums[blockIdx.x] = sh[t];    // block total
}

__global__ void __launch_bounds__(256) k_scan2(int* __restrict__ sums) {
    __shared__ int sh[256];
    int t = threadIdx.x;
    int val = (t < NBLK) ? sums[t] : 0;
    sh[t] = val;
    __syncthreads();
    for (int o = 1; o < 256; o <<= 1) {
        int x = (t >= o) ? sh[t - o] : 0;
        __syncthreads();
        sh[t] += x;
        __syncthreads();
    }
    if (t < NBLK) sums[t] = sh[t] - val;              // exclusive block offsets
}

// rowptr finalize + second copy for k_fill's direct atomicAdd (saves a scattered
// rowptr read per edge in k_fill).
__global__ void __launch_bounds__(SCAN_B) k_scan3(int* __restrict__ rowptr,
                                                  const int* __restrict__ sums,
                                                  int* __restrict__ fillptr) {
    int i = blockIdx.x * SCAN_B + threadIdx.x;
    if (i < NGRAPH) {
        int v = rowptr[i] + sums[blockIdx.x];
        rowptr[i] = v;
        fillptr[i] = v;
    }
}

// ---------- scatter edges into packed CSR slots: int2{src, w-bits} ----------
__global__ void k_fill(const int* __restrict__ ei, const int* __restrict__ flag,
                       const float* __restrict__ dinv,
                       int* __restrict__ fillptr, int2* __restrict__ csr) {
    int e = blockIdx.x * blockDim.x + threadIdx.x;
    if (e >= NEDGE) return;
    int is64 = flag[0];
    int s = e_src(ei, is64, e);
    int d = e_dst(ei, is64, e);
    int pos = atomicAdd(&fillptr[d], 1);
    csr[pos] = make_int2(s, __float_as_int(dinv[s] * dinv[d]));
}

// ---------- fused GCN layer 1: CSR agg (7-dim) + [7->128] matmul + ReLU -> fp16 x1 ----
__global__ void __launch_bounds__(256) k_gcn1(const int* __restrict__ rowptr,
                                              const int* __restrict__ deg,
                                              const int2* __restrict__ csr,
                                              const float* __restrict__ dinv,
                                              const float* __restrict__ comb,
                                              const float* __restrict__ W1,
                                              const float* __restrict__ b1,
                                              __half* __restrict__ x1) {
    __shared__ float agg_s[32][8];
    int g = threadIdx.x >> 3;                  // node within block
    int f = threadIdx.x & 7;
    int d = blockIdx.x * 32 + g;
    if (f < 7) {
        int start = rowptr[d], n = deg[d];
        float acc = 0.0f;
        int j = 0;
        for (; j + 2 <= n; j += 2) {           // 2 independent comb gathers in flight
            int2 e0 = csr[start + j];
            int2 e1 = csr[start + j + 1];
            float c0 = comb[e0.x * 7 + f];
            float c1 = comb[e1.x * 7 + f];
            acc = fmaf(__int_as_float(e0.y), c0, acc);
            acc = fmaf(__int_as_float(e1.y), c1, acc);
        }
        if (j < n) {
            int2 e0 = csr[start + j];
            acc = fmaf(__int_as_float(e0.y), comb[e0.x * 7 + f], acc);
        }
        float dv = dinv[d];
        acc = fmaf(dv * dv, comb[d * 7 + f], acc);    // self loop
        agg_s[g][f] = acc;
    }
    __syncthreads();
    float a[7];
    #pragma unroll
    for (int q = 0; q < 7; ++q) a[q] = agg_s[g][q];   // LDS broadcast per node
    int h0 = f * 16;
    #pragma unroll
    for (int j = 0; j < 4; ++j) {
        int h = h0 + j * 4;
        float4 acc4 = *reinterpret_cast<const float4*>(b1 + h);
        #pragma unroll
        for (int q = 0; q < 7; ++q) {
            float4 w = *reinterpret_cast<const float4*>(W1 + q * HID + h);
            acc4.x = fmaf(a[q], w.x, acc4.x);
            acc4.y = fmaf(a[q], w.y, acc4.y);
            acc4.z = fmaf(a[q], w.z, acc4.z);
            acc4.w = fmaf(a[q], w.w, acc4.w);
        }
        __half2 h01 = __floats2half2_rn(fmaxf(acc4.x, 0.0f), fmaxf(acc4.y, 0.0f));
        __half2 h23 = __floats2half2_rn(fmaxf(acc4.z, 0.0f), fmaxf(acc4.w, 0.0f));
        uint2 pk;
        pk.x = *reinterpret_cast<unsigned int*>(&h01);
        pk.y = *reinterpret_cast<unsigned int*>(&h23);
        *reinterpret_cast<uint2*>(x1 + (size_t)d * HID + h) = pk;   // 8B aligned
    }
}

// ---------- layer-2 agg over CSR: 1 wave/node, lane holds 2 of 128 feats (fp16 x1) ----
// 4-way unrolled: four independent 256B row-gathers in flight (r11: gather-BW-bound).
__global__ void __launch_bounds__(256) k_agg2(const int* __restrict__ rowptr,
                                              const int* __restrict__ deg,
                                              const int2* __restrict__ csr,
                                              const float* __restrict__ dinv,
                                              const __half2* __restrict__ x1,
                                              float* __restrict__ agg2) {
    int wave = threadIdx.x >> 6;
    int lane = threadIdx.x & 63;
    int d = blockIdx.x * 4 + wave;
    int f0 = lane * 2;
    int start = rowptr[d], n = deg[d];
    float2 acc = {0.0f, 0.0f};
    int j = 0;
    for (; j + 4 <= n; j += 4) {
        int2 e0 = csr[start + j];
        int2 e1 = csr[start + j + 1];
        int2 e2 = csr[start + j + 2];
        int2 e3 = csr[start + j + 3];
        float2 v0 = __half22float2(x1[(size_t)e0.x * 64 + lane]);
        float2 v1 = __half22float2(x1[(size_t)e1.x * 64 + lane]);
        float2 v2 = __half22float2(x1[(size_t)e2.x * 64 + lane]);
        float2 v3 = __half22float2(x1[(size_t)e3.x * 64 + lane]);
        acc.x = fmaf(__int_as_float(e0.y), v0.x, acc.x);
        acc.y = fmaf(__int_as_float(e0.y), v0.y, acc.y);
        acc.x = fmaf(__int_as_float(e1.y), v1.x, acc.x);
        acc.y = fmaf(__int_as_float(e1.y), v1.y, acc.y);
        acc.x = fmaf(__int_as_float(e2.y), v2.x, acc.x);
        acc.y = fmaf(__int_as_float(e2.y), v2.y, acc.y);
        acc.x = fmaf(__int_as_float(e3.y), v3.x, acc.x);
        acc.y = fmaf(__int_as_float(e3.y), v3.y, acc.y);
    }
    for (; j < n; ++j) {
        int2 e0 = csr[start + j];
        float2 v0 = __half22float2(x1[(size_t)e0.x * 64 + lane]);
        acc.x = fmaf(__int_as_float(e0.y), v0.x, acc.x);
        acc.y = fmaf(__int_as_float(e0.y), v0.y, acc.y);
    }
    float dv = dinv[d];
    float ws = dv * dv;
    float2 v = __half22float2(x1[(size_t)d * 64 + lane]);
    acc.x = fmaf(ws, v.x, acc.x);
    acc.y = fmaf(ws, v.y, acc.y);
    *reinterpret_cast<float2*>(agg2 + (size_t)d * HID + f0) = acc;
}

// ---------- fused dense tail, LDS-resident, 4-node x (4+4)-output register blocking ----
// r13-verified structure: conflict-free (hA=tx*4, hB=64+tx*4), 101us, LDS-throughput
// bound. r15's gather fusion REGRESSED (334us: phase-0 lost TLP, 4-way write
// conflicts) -- keep k_agg2 separate.
__device__ __forceinline__ void fmad(float4& acc, float s, const float4 w) {
    acc.x = fmaf(s, w.x, acc.x);
    acc.y = fmaf(s, w.y, acc.y);
    acc.z = fmaf(s, w.z, acc.z);
    acc.w = fmaf(s, w.w, acc.w);
}
__device__ __forceinline__ float4 relu4(float4 v) {
    float4 r;
    r.x = fmaxf(v.x, 0.0f); r.y = fmaxf(v.y, 0.0f);
    r.z = fmaxf(v.z, 0.0f); r.w = fmaxf(v.w, 0.0f);
    return r;
}

__global__ void __launch_bounds__(256, 3) k_mlp(const float* __restrict__ agg2,
                                                const float* __restrict__ W2,
                                                const float* __restrict__ b2,
                                                const float* __restrict__ fc1w,
                                                const float* __restrict__ fc1b,
                                                const float* __restrict__ fc2w,
                                                const float* __restrict__ fc2b,
                                                float* __restrict__ out) {
    __shared__ float as_[TILE][LPAD];      // activation tile, then x2 tile
    __shared__ float ws[32][LPAD];         // 32 staged weight rows
    const int tid = threadIdx.x;
    const int tx = tid & 15;               // two output cols: hA=tx*4, hB=64+tx*4
    const int ty = tid >> 4;               // nodes ty*4 .. ty*4+3
    const int n0 = blockIdx.x * TILE;      // tail block: 32 valid nodes, guarded
    const int hA = tx * 4;
    const int hB = 64 + tx * 4;

    // stage activations: 64 rows x 128 floats = 2048 f4, 8 per thread (clamped rows)
    #pragma unroll
    for (int q = 0; q < 8; ++q) {
        int idx = (q * 256 + tid) * 4;
        int row = idx >> 7, col = idx & 127;
        int nr = n0 + row; if (nr >= NGRAPH) nr = NGRAPH - 1;
        *reinterpret_cast<float4*>(&as_[row][col]) =
            *reinterpret_cast<const float4*>(agg2 + (size_t)nr * HID + col);
    }

    // ---- phase A: x2 = relu(agg2 @ W2 + b2) ----
    float4 cA[4], cB[4];
    {
        float4 bA = *reinterpret_cast<const float4*>(b2 + hA);
        float4 bB = *reinterpret_cast<const float4*>(b2 + hB);
        #pragma unroll
        for (int r = 0; r < 4; ++r) { cA[r] = bA; cB[r] = bB; }
    }
    for (int ks = 0; ks < HID; ks += 32) {
        #pragma unroll
        for (int q = 0; q < 4; ++q) {
            int idx = (q * 256 + tid) * 4;
            int row = idx >> 7, col = idx & 127;
            *reinterpret_cast<float4*>(&ws[row][col]) =
                *reinterpret_cast<const float4*>(W2 + (size_t)(ks + row) * HID + col);
        }
        __syncthreads();                    // also covers as_ staging on ks==0
        #pragma unroll
        for (int k = 0; k < 32; k += 4) {
            float4 wA0 = *reinterpret_cast<const float4*>(&ws[k + 0][hA]);
            float4 wB0 = *reinterpret_cast<const float4*>(&ws[k + 0][hB]);
            float4 wA1 = *reinterpret_cast<const float4*>(&ws[k + 1][hA]);
            float4 wB1 = *reinterpret_cast<const float4*>(&ws[k + 1][hB]);
            float4 wA2 = *reinterpret_cast<const float4*>(&ws[k + 2][hA]);
            float4 wB2 = *reinterpret_cast<const float4*>(&ws[k + 2][hB]);
            float4 wA3 = *reinterpret_cast<const float4*>(&ws[k + 3][hA]);
            float4 wB3 = *reinterpret_cast<const float4*>(&ws[k + 3][hB]);
            #pragma unroll
            for (int r = 0; r < 4; ++r) {
                float4 a = *reinterpret_cast<const float4*>(&as_[ty * 4 + r][ks + k]);
                fmad(cA[r], a.x, wA0); fmad(cB[r], a.x, wB0);
                fmad(cA[r], a.y, wA1); fmad(cB[r], a.y, wB1);
                fmad(cA[r], a.z, wA2); fmad(cB[r], a.z, wB2);
                fmad(cA[r], a.w, wA3); fmad(cB[r], a.w, wB3);
            }
        }
        __syncthreads();                    // protect ws for next stage
    }
    // write x2 into as_ (all phase-A reads completed at the trailing sync)
    #pragma unroll
    for (int r = 0; r < 4; ++r) {
        *reinterpret_cast<float4*>(&as_[ty * 4 + r][hA]) = relu4(cA[r]);
        *reinterpret_cast<float4*>(&as_[ty * 4 + r][hB]) = relu4(cB[r]);
    }

    // ---- phase B: x3 = relu(x2 @ fc1w + fc1b) ----
    float4 dA[4], dB[4];
    {
        float4 bA = *reinterpret_cast<const float4*>(fc1b + hA);
        float4 bB = *reinterpret_cast<const float4*>(fc1b + hB);
        #pragma unroll
        for (int r = 0; r < 4; ++r) { dA[r] = bA; dB[r] = bB; }
    }
    for (int ks = 0; ks < HID; ks += 32) {
        #pragma unroll
        for (int q = 0; q < 4; ++q) {
            int idx = (q * 256 + tid) * 4;
            int row = idx >> 7, col = idx & 127;
            *reinterpret_cast<float4*>(&ws[row][col]) =
                *reinterpret_cast<const float4*>(fc1w + (size_t)(ks + row) * HID + col);
        }
        __syncthreads();                    // also makes x2 writes visible (ks==0)
        #pragma unroll
        for (int k = 0; k < 32; k += 4) {
            float4 wA0 = *reinterpret_cast<const float4*>(&ws[k + 0][hA]);
            float4 wB0 = *reinterpret_cast<const float4*>(&ws[k + 0][hB]);
            float4 wA1 = *reinterpret_cast<const float4*>(&ws[k + 1][hA]);
            float4 wB1 = *reinterpret_cast<const float4*>(&ws[k + 1][hB]);
            float4 wA2 = *reinterpret_cast<const float4*>(&ws[k + 2][hA]);
            float4 wB2 = *reinterpret_cast<const float4*>(&ws[k + 2][hB]);
            float4 wA3 = *reinterpret_cast<const float4*>(&ws[k + 3][hA]);
            float4 wB3 = *reinterpret_cast<const float4*>(&ws[k + 3][hB]);
            #pragma unroll
            for (int r = 0; r < 4; ++r) {
                float4 a = *reinterpret_cast<const float4*>(&as_[ty * 4 + r][ks + k]);
                fmad(dA[r], a.x, wA0); fmad(dB[r], a.x, wB0);
                fmad(dA[r], a.y, wA1); fmad(dB[r], a.y, wB1);
                fmad(dA[r], a.z, wA2); fmad(dB[r], a.z, wB2);
                fmad(dA[r], a.w, wA3); fmad(dB[r], a.w, wB3);
            }
        }
        __syncthreads();
    }

    // ---- phase C: out = x3 @ fc2w + fc2b (reduce over 16 tx lanes) ----
    float4 wqA = *reinterpret_cast<const float4*>(fc2w + hA);
    float4 wqB = *reinterpret_cast<const float4*>(fc2w + hB);
    float p[4];
    #pragma unroll
    for (int r = 0; r < 4; ++r) {
        float4 rA = relu4(dA[r]);
        float4 rB = relu4(dB[r]);
        p[r] = rA.x * wqA.x + rA.y * wqA.y + rA.z * wqA.z + rA.w * wqA.w
             + rB.x * wqB.x + rB.y * wqB.y + rB.z * wqB.z + rB.w * wqB.w;
    }
    #pragma unroll
    for (int m = 1; m < 16; m <<= 1) {     // xor-mask < 16 stays within the tx group
        #pragma unroll
        for (int r = 0; r < 4; ++r) p[r] += __shfl_xor(p[r], m);
    }
    if (tx == 0) {
        float bq = fc2b[0];
        int nb = n0 + ty * 4;
        #pragma unroll
        for (int r = 0; r < 4; ++r)
            if (nb + r < NGRAPH) out[nb + r] = p[r] + bq;
    }
}

extern "C" void kernel_launch(void* const* d_in, const int* in_sizes, int n_in,
                              void* d_out, int out_size, void* d_ws, size_t ws_size,
                              hipStream_t stream) {
    const float* obs  = (const float*)d_in[0];
    const int*   ei   = (const int*)d_in[1];
    const float* W1   = (const float*)d_in[2];
    const float* b1   = (const float*)d_in[3];
    const float* W2   = (const float*)d_in[4];
    const float* b2   = (const float*)d_in[5];
    const float* fc1w = (const float*)d_in[6];
    const float* fc1b = (const float*)d_in[7];
    const float* fc2w = (const float*)d_in[8];
    const float* fc2b = (const float*)d_in[9];
    float* out = (float*)d_out;

    char* base = (char*)d_ws;
    size_t off = 0;
    auto take = [&](size_t bytes) {
        char* p = base + off;
        off += (bytes + 255) & ~(size_t)255;
        return p;
    };
    int*    deg     = (int*)take((size_t)NGRAPH * 4);
    int*    rowptr  = (int*)take((size_t)NGRAPH * 4);
    int*    fillptr = (int*)take((size_t)NGRAPH * 4);
    int*    sums    = (int*)take((size_t)NBLK * 4);
    float*  dinv    = (float*)take((size_t)NGRAPH * 4);
    int2*   csr     = (int2*)take((size_t)NEDGE * 8);
    float*  comb    = (float*)take((size_t)NGRAPH * 7 * 4);
    __half* x1      = (__half*)take((size_t)NGRAPH * HID * 2);
    float*  agg2    = (float*)take((size_t)NGRAPH * HID * 4);
    int*    flag    = (int*)take(256);

    k_prep<<<(NGRAPH + 255) / 256, 256, 0, stream>>>(obs, ei, comb, deg, flag);
    k_deg<<<(NEDGE + 255) / 256, 256, 0, stream>>>(ei, flag, deg);
    k_scan1<<<NBLK, SCAN_B, 0, stream>>>(deg, rowptr, sums, dinv);
    k_scan2<<<1, 256, 0, stream>>>(sums);
    k_scan3<<<NBLK, SCAN_B, 0, stream>>>(rowptr, sums, fillptr);
    k_fill<<<(NEDGE + 255) / 256, 256, 0, stream>>>(ei, flag, dinv, fillptr, csr);
    k_gcn1<<<NGRAPH / 32, 256, 0, stream>>>(rowptr, deg, csr, dinv,
                                            comb, W1, b1, x1);
    k_agg2<<<NGRAPH / 4, 256, 0, stream>>>(rowptr, deg, csr, dinv,
                                           (const __half2*)x1, agg2);
    k_mlp<<<(NGRAPH + TILE - 1) / TILE, 256, 0, stream>>>(agg2, W2, b2,
                                                          fc1w, fc1b,
                                                          fc2w, fc2b, out);
}